// Round 5
// baseline (245.206 us; speedup 1.0000x reference)
//
#include <hip/hip_runtime.h>

// Problem constants (reference: L=4, B=32, T=2048, D=100)
constexpr int kL = 4;
constexpr int kB = 32;
constexpr int kT = 2048;
constexpr int kD = 100;
constexpr int kD4 = kD / 4;            // 25 float4 per row
constexpr int kROWS = kL * kB * kD;    // 12800 (l,b,d) softmax rows
constexpr int kRPB = 256;              // rows (t) per block
constexpr int kRPC = 64;               // rows per chunk: 64*400B = 25*1024B exactly
constexpr int kNC = kRPB / kRPC;       // 4 chunks per block
constexpr int kF4C = kRPC * kD4;       // 1600 float4 per array-chunk (25.6 KB)
constexpr int kLoads = kF4C / 64;      // 25 full-wave 1024B loads per array-chunk

// Fire-and-forget global->LDS DMA, 16B per lane, all 64 lanes.
// LDS dest semantics: wave-uniform base + lane*16 (m104/m108) -- our lds ptr is
// exactly base + lane, matching.
__device__ __forceinline__ void gload_lds16(const float4* g, float4* l) {
  __builtin_amdgcn_global_load_lds(
      (const __attribute__((address_space(1))) void*)g,
      (__attribute__((address_space(3))) void*)l, 16, 0, 0);
}

// Pass 1: per-row partial sums, LDS-staged (m97-style 2-barrier K-loop).
//   S_p = sum_t exp(old_h), S_q = sum_t exp(h), W = sum_t exp(old_h)*(old_h-h)
// No max-subtraction: N(0,1) logits, exp cannot overflow fp32 (absmax=0 R1-R4).
// R5 theory: R1-R4 all pinned at ~80us / ~2.6 TB/s because the VGPR-return load
// path holds only ~2 wave-loads in flight. global_load_lds has no VGPR dest ->
// ~13 loads in flight per wave, 64/64 lanes, 1KB contiguous per instruction.
__global__ __launch_bounds__(256) void kl_partial(
    const float4* __restrict__ h4, const float4* __restrict__ oh4,
    float* __restrict__ wsp, float* __restrict__ wsq, float* __restrict__ ww) {
  __shared__ float4 smem[2 * kF4C];    // [0,1600): h rows; [1600,3200): oh rows. 51.2 KB
  const int lb = blockIdx.x >> 3;      // (l*B+b) in [0,128)
  const int blk8 = blockIdx.x & 7;     // which 256-row band of the slab
  const int tid = threadIdx.x;
  const int wv = tid >> 6;             // wave 0..3
  const int lane = tid & 63;
  const int half = lane / kD4;         // consume map: 0,1 active; lanes 50..63 idle
  const int d4 = lane - half * kD4;
  const bool active = lane < 2 * kD4;

  const size_t slab = (size_t)lb * kT * kD4;
  const int row0 = blk8 * kRPB;

  float4 sp = {0.f, 0.f, 0.f, 0.f};
  float4 sq = {0.f, 0.f, 0.f, 0.f};
  float4 w  = {0.f, 0.f, 0.f, 0.f};

  for (int c = 0; c < kNC; ++c) {
    // --- stage chunk c: 25+25 full-wave 1KB DMAs split over 4 waves ---
    const size_t cbase = slab + (size_t)(row0 + c * kRPC) * kD4;
    const float4* gh = h4 + cbase + lane;
    const float4* go = oh4 + cbase + lane;
    for (int j = wv; j < kLoads; j += 4) {
      gload_lds16(gh + j * 64, smem + j * 64 + lane);
      gload_lds16(go + j * 64, smem + kF4C + j * 64 + lane);
    }
    __syncthreads();  // drains vmcnt -> LDS writes visible
    // --- consume chunk c from LDS (50-lane row pattern, ds_read_b128) ---
    if (active) {
#pragma unroll
      for (int p = 0; p < 8; ++p) {
        const int r = 2 * wv + half + 8 * p;     // covers rows 0..63 exactly once
        const float4 hv = smem[r * kD4 + d4];
        const float4 ov = smem[kF4C + r * kD4 + d4];
        const float a = __expf(ov.x), b = __expf(ov.y),
                    cc = __expf(ov.z), dd = __expf(ov.w);
        sp.x += a; sp.y += b; sp.z += cc; sp.w += dd;
        sq.x += __expf(hv.x); sq.y += __expf(hv.y);
        sq.z += __expf(hv.z); sq.w += __expf(hv.w);
        w.x += a * (ov.x - hv.x); w.y += b * (ov.y - hv.y);
        w.z += cc * (ov.z - hv.z); w.w += dd * (ov.w - hv.w);
      }
    }
    __syncthreads();  // protect smem before next stage overwrites
  }

  // --- epilogue: block reduce (8 contributors per d), 3 atomics/d ---
  float* red = (float*)smem;           // alias staging buffer (post-barrier)
  {
    float* rr = red + tid * 12;
    rr[0] = sp.x; rr[1] = sp.y; rr[2]  = sp.z; rr[3]  = sp.w;
    rr[4] = sq.x; rr[5] = sq.y; rr[6]  = sq.z; rr[7]  = sq.w;
    rr[8] = w.x;  rr[9] = w.y;  rr[10] = w.z;  rr[11] = w.w;
  }
  __syncthreads();
  if (tid < kD) {
    const int dd4 = tid >> 2, j = tid & 3;
    float asp = 0.f, asq = 0.f, aw = 0.f;
#pragma unroll
    for (int g = 0; g < 4; ++g) {
#pragma unroll
      for (int hh = 0; hh < 2; ++hh) {
        const float* s = red + (g * 64 + hh * kD4 + dd4) * 12;
        asp += s[j]; asq += s[4 + j]; aw += s[8 + j];
      }
    }
    const int idx = lb * kD + tid;
    atomicAdd(&wsp[idx], asp);
    atomicAdd(&wsq[idx], asq);
    atomicAdd(&ww[idx],  aw);
  }
}

// Pass 2: 50 blocks x 256 threads, one thread per (l,b,d) row.
__global__ __launch_bounds__(256) void kl_reduce(
    const float* __restrict__ wsp, const float* __restrict__ wsq,
    const float* __restrict__ ww, const float* __restrict__ lwin,
    const float* __restrict__ cwin, float* __restrict__ acc) {
  __shared__ float lw[kL];
  __shared__ float cw[kD];
  __shared__ float sred[256];
  const int tid = threadIdx.x;

  if (tid == 0) {
    float m = lwin[0];
    for (int i = 1; i < kL; ++i) m = fmaxf(m, lwin[i]);
    float e[kL], s = 0.f;
    for (int i = 0; i < kL; ++i) { e[i] = __expf(lwin[i] - m); s += e[i]; }
    const float inv = 1.0f / s;
    for (int i = 0; i < kL; ++i) lw[i] = e[i] * inv;
  }
  if (tid == 64) {
    float m = cwin[0];
    for (int i = 1; i < kD; ++i) m = fmaxf(m, cwin[i]);
    float s = 0.f;
    for (int i = 0; i < kD; ++i) { const float e = __expf(cwin[i] - m); cw[i] = e; s += e; }
    const float inv = 1.0f / s;
    for (int i = 0; i < kD; ++i) cw[i] *= inv;
  }
  __syncthreads();

  const int r = blockIdx.x * 256 + tid;          // < 12800 (grid = 50)
  const int l = r / (kB * kD);
  const int d = r % kD;
  const float spv = wsp[r], sqv = wsq[r], wv = ww[r];
  const float val = wv / spv - __logf(spv) + __logf(sqv);
  sred[tid] = lw[l] * cw[d] * val;
  __syncthreads();
  for (int s = 128; s > 0; s >>= 1) {
    if (tid < s) sred[tid] += sred[tid + s];
    __syncthreads();
  }
  if (tid == 0) atomicAdd(acc, sred[0]);
}

__global__ void kl_write(const float* __restrict__ acc, float* __restrict__ out) {
  out[0] = acc[0] / (float)kB;
}

extern "C" void kernel_launch(void* const* d_in, const int* in_sizes, int n_in,
                              void* d_out, int out_size, void* d_ws, size_t ws_size,
                              hipStream_t stream) {
  const float* h    = (const float*)d_in[0];  // [L,B,T,D] fp32
  const float* oh   = (const float*)d_in[1];  // [L,B,T,D] fp32
  const float* lwin = (const float*)d_in[2];  // [L] fp32
  const float* cwin = (const float*)d_in[3];  // [D] fp32

  float* wsp = (float*)d_ws;        // [kROWS] S_p (atomic-accumulated)
  float* wsq = wsp + kROWS;         // [kROWS] S_q
  float* ww  = wsq + kROWS;         // [kROWS] W
  float* acc = ww + kROWS;          // [1] weighted scalar accumulator
  hipMemsetAsync(d_ws, 0, ((size_t)3 * kROWS + 1) * sizeof(float), stream);

  kl_partial<<<kL * kB * (kT / kRPB), 256, 0, stream>>>(
      (const float4*)h, (const float4*)oh, wsp, wsq, ww);
  kl_reduce<<<kROWS / 256, 256, 0, stream>>>(wsp, wsq, ww, lwin, cwin, acc);
  kl_write<<<1, 1, 0, stream>>>(acc, (float*)d_out);
}